// Round 13
// baseline (259.215 us; speedup 1.0000x reference)
//
#include <hip/hip_runtime.h>
#include <hip/hip_bf16.h>

#define N_NODES 100000
#define N_EDGES 3200000

#define NTH   1024
#define CBLK  500                    // count/compact blocks
#define EPB   (N_EDGES / CBLK)       // 6400
#define NI4   (EPB / 4)              // 1600 int4-slots per block (1600 % 64 == 0)
#define NWAVE 16
#define NSLOT (CBLK * NWAVE)         // 8000 wave-slots

#define P_PARTS 8
#define PART    12800                // p = dst / 12800 (8*12800 = 102400 >= N)
#define CHUNKS  64
#define HBLOCKS (P_PARTS * CHUNKS)   // 512

// ---------------- workspace layout (bytes) ----------------
#define OFF_BPART  0         // double[500*5]
#define OFF_CONST  20032     // float[136]
#define OFF_PSTART 20608     // int[16]
#define OFF_WCNT   20672     // int[8000*8]
#define OFF_SBASE  276672    // int[8000*8]
#define OFF_DEG    532672    // float[102400] (zeroed by count)
#define OFF_ACC    942272    // float[102400]
#define OFF_DINV   1351872   // float[100000]
#define OFF_GS     1751872   // float[100000]
#define OFF_BUCKET 2151872   // uint[3200000] -> ends ~15 MB

// per-wave int64-vs-int32 detection: high words of first 64 int64 slots
__device__ __forceinline__ bool detect_is64(const void* ei) {
    const int* p = (const int*)ei;
    int lane = threadIdx.x & 63;
    int hi = p[2 * lane + 1];
    unsigned long long m = __ballot(hi != 0);
    return m == 0ull;  // wave-uniform
}

__device__ __forceinline__ int4 load_dst4(const void* ei, bool is64, int i4) {
    if (is64) {
        const longlong2* dp = (const longlong2*)((const long long*)ei + N_EDGES);
        longlong2 a = dp[2 * i4];
        longlong2 b = dp[2 * i4 + 1];
        return make_int4((int)a.x, (int)a.y, (int)b.x, (int)b.y);
    }
    return ((const int4*)((const int*)ei + N_EDGES))[i4];
}

__device__ __forceinline__ int4 load_src4(const void* ei, bool is64, int i4) {
    if (is64) {
        const longlong2* sp = (const longlong2*)ei;
        longlong2 a = sp[2 * i4];
        longlong2 b = sp[2 * i4 + 1];
        return make_int4((int)a.x, (int)a.y, (int)b.x, (int)b.y);
    }
    return ((const int4*)ei)[i4];
}

// ---- K1: per-(block,wave,part) edge counts + BN partials + zero degf ----
__global__ __launch_bounds__(NTH, 8) void count_kernel(
        const float* __restrict__ x, const void* __restrict__ ei,
        double* __restrict__ bpart, int* __restrict__ wcnt, float* __restrict__ degf) {
    __shared__ double sh[5][16];
    bool is64 = detect_is64(ei);
    int lane = threadIdx.x & 63, w = threadIdx.x >> 6;
    int tid = blockIdx.x * NTH + threadIdx.x;

    for (int i = tid; i < P_PARTS * PART; i += CBLK * NTH) degf[i] = 0.f;

    // BN stats partial
    {
        double a0 = 0, a1 = 0, a2 = 0, a3 = 0, a4 = 0;
        if (tid < N_NODES) {
            float2 v = ((const float2*)x)[tid];
            double x0 = v.x, x1 = v.y;
            a0 = x0; a1 = x1; a2 = x0 * x0; a3 = x1 * x1; a4 = x0 * x1;
        }
        for (int off = 32; off; off >>= 1) {
            a0 += __shfl_down(a0, off);
            a1 += __shfl_down(a1, off);
            a2 += __shfl_down(a2, off);
            a3 += __shfl_down(a3, off);
            a4 += __shfl_down(a4, off);
        }
        if (lane == 0) {
            sh[0][w] = a0; sh[1][w] = a1; sh[2][w] = a2; sh[3][w] = a3; sh[4][w] = a4;
        }
        __syncthreads();
        if (threadIdx.x == 0) {
            double t0 = 0, t1 = 0, t2 = 0, t3 = 0, t4 = 0;
            for (int i = 0; i < 16; i++) {
                t0 += sh[0][i]; t1 += sh[1][i]; t2 += sh[2][i]; t3 += sh[3][i]; t4 += sh[4][i];
            }
            double* bp = bpart + blockIdx.x * 5;
            bp[0] = t0; bp[1] = t1; bp[2] = t2; bp[3] = t3; bp[4] = t4;
        }
    }

    // register counters over this block's int4 slots
    int cnt[P_PARTS];
#pragma unroll
    for (int pp = 0; pp < P_PARTS; pp++) cnt[pp] = 0;
    int base_i4 = blockIdx.x * NI4;
    for (int k = threadIdx.x; k < NI4; k += NTH) {
        int4 d4 = load_dst4(ei, is64, base_i4 + k);
        int p0 = (int)((unsigned)d4.x / PART);
        int p1 = (int)((unsigned)d4.y / PART);
        int p2 = (int)((unsigned)d4.z / PART);
        int p3 = (int)((unsigned)d4.w / PART);
#pragma unroll
        for (int pp = 0; pp < P_PARTS; pp++)
            cnt[pp] += (p0 == pp) + (p1 == pp) + (p2 == pp) + (p3 == pp);
    }
#pragma unroll
    for (int pp = 0; pp < P_PARTS; pp++) {
        int v = cnt[pp];
        for (int off = 32; off; off >>= 1) v += __shfl_down(v, off);
        if (lane == 0) wcnt[(blockIdx.x * NWAVE + w) * P_PARTS + pp] = v;
    }
}

// ---- K2 (1 block): exclusive scan of wave-slot counts + partition starts + consts ----
__global__ __launch_bounds__(NTH) void scan_kernel(
        const int* __restrict__ wcnt, int* __restrict__ sbase, int* __restrict__ pstart,
        const double* __restrict__ bpart,
        const float* __restrict__ w1, const float* __restrict__ b1,
        const float* __restrict__ gamma, const float* __restrict__ beta,
        const float* __restrict__ w2, const float* __restrict__ b2,
        const float* __restrict__ gcn_w, const float* __restrict__ wb,
        const float* __restrict__ gcn_b, const float* __restrict__ bb,
        float* __restrict__ consts) {
    __shared__ int wsum[16];
    __shared__ float sV[32];
    __shared__ double red[16][5];
    int t = threadIdx.x;
    int lane = t & 63, w = t >> 6;
    int run = 0;

    for (int p = 0; p < P_PARTS; p++) {
        int loc[8];
        int s = 0;
        if (t < NSLOT / 8) {  // 1000 threads, 8 slots each
#pragma unroll
            for (int j = 0; j < 8; j++) {
                loc[j] = s;
                s += wcnt[(t * 8 + j) * P_PARTS + p];
            }
        }
        int sv = s;
        for (int off = 1; off < 64; off <<= 1) {
            int u = __shfl_up(sv, off, 64);
            if (lane >= off) sv += u;
        }
        if (lane == 63) wsum[w] = sv;
        __syncthreads();
        if (w == 0) {
            int pv = (lane < 16) ? wsum[lane] : 0;
            for (int off = 1; off < 16; off <<= 1) {
                int u = __shfl_up(pv, off, 64);
                if (lane >= off) pv += u;
            }
            if (lane < 16) wsum[lane] = pv;
        }
        __syncthreads();
        int excl = sv - s + (w > 0 ? wsum[w - 1] : 0);
        if (t < NSLOT / 8) {
#pragma unroll
            for (int j = 0; j < 8; j++)
                sbase[(t * 8 + j) * P_PARTS + p] = run + excl + loc[j];
        }
        if (t == 0) pstart[p] = run;
        run += wsum[15];
        __syncthreads();
    }
    if (t == 0) pstart[P_PARTS] = run;  // == N_EDGES

    // ---- consts from bpart ----
    double r0 = 0, r1 = 0, r2 = 0, r3 = 0, r4 = 0;
    if (t < CBLK) {
        const double* bp = bpart + t * 5;
        r0 = bp[0]; r1 = bp[1]; r2 = bp[2]; r3 = bp[3]; r4 = bp[4];
    }
    for (int off = 32; off; off >>= 1) {
        r0 += __shfl_down(r0, off);
        r1 += __shfl_down(r1, off);
        r2 += __shfl_down(r2, off);
        r3 += __shfl_down(r3, off);
        r4 += __shfl_down(r4, off);
    }
    if (lane == 0) {
        red[w][0] = r0; red[w][1] = r1; red[w][2] = r2; red[w][3] = r3; red[w][4] = r4;
    }
    __syncthreads();
    if (t < 32) {
        int c = t;
        double s0 = 0, s1 = 0, s2 = 0, s3 = 0, s4 = 0;
        for (int i = 0; i < 16; i++) {
            s0 += red[i][0]; s1 += red[i][1]; s2 += red[i][2];
            s3 += red[i][3]; s4 += red[i][4];
        }
        double invN = 1.0 / (double)N_NODES;
        double m0 = s0 * invN, m1 = s1 * invN;
        double e00 = s2 * invN, e11 = s3 * invN, e01 = s4 * invN;
        double a = w1[2 * c], b = w1[2 * c + 1], tt = b1[c];
        double meanH = a * m0 + b * m1 + tt;
        double eh2 = a * a * e00 + b * b * e11 + 2.0 * a * b * e01 +
                     2.0 * tt * (a * m0 + b * m1) + tt * tt;
        double var = eh2 - meanH * meanH;
        double inv = 1.0 / sqrt(var + 1e-5);
        float sc = (float)((double)gamma[c] * inv);
        float shift = beta[c] - (float)meanH * sc;
        consts[c]      = (float)a * sc;
        consts[32 + c] = (float)b * sc;
        consts[64 + c] = (float)tt * sc + shift;
        float vc = 0.f;
        for (int j = 0; j < 32; j++) vc += wb[j] * gcn_w[j * 32 + c];
        sV[c] = vc;
    }
    __syncthreads();
    if (t < 32) {
        float u = 0.f;
        for (int c = 0; c < 32; c++) u += sV[c] * w2[c * 32 + t];
        consts[96 + t] = u;
        float gb = b2[t] * sV[t];
        for (int off = 16; off; off >>= 1) gb += __shfl_down(gb, off, 32);
        float pv = wb[t] * gcn_b[t];
        for (int off = 16; off; off >>= 1) pv += __shfl_down(pv, off, 32);
        if (t == 0) {
            consts[128] = gb;            // GB = b2 . v
            consts[129] = pv + bb[0];    // SCC
        }
    }
}

// ---- K3: atomic-free compact via per-wave exact bases + ballot ranking ----
__global__ __launch_bounds__(NTH, 8) void compact_kernel(
        const void* __restrict__ ei, const int* __restrict__ sbase,
        unsigned* __restrict__ bucket) {
    bool is64 = detect_is64(ei);
    int lane = threadIdx.x & 63, w = threadIdx.x >> 6;
    unsigned long long below = (1ull << lane) - 1ull;
    int slot = blockIdx.x * NWAVE + w;
    int off[P_PARTS];
#pragma unroll
    for (int pp = 0; pp < P_PARTS; pp++) off[pp] = sbase[slot * P_PARTS + pp];

    int base_i4 = blockIdx.x * NI4;
    for (int k = threadIdx.x; k < NI4; k += NTH) {
        int4 d4 = load_dst4(ei, is64, base_i4 + k);
        int4 s4 = load_src4(ei, is64, base_i4 + k);
        int dd[4] = {d4.x, d4.y, d4.z, d4.w};
        int ss[4] = {s4.x, s4.y, s4.z, s4.w};
#pragma unroll
        for (int j = 0; j < 4; j++) {
            int p = (int)((unsigned)dd[j] / PART);
            unsigned packed = (unsigned)ss[j] | ((unsigned)(dd[j] - p * PART) << 17);
#pragma unroll
            for (int pp = 0; pp < P_PARTS; pp++) {
                unsigned long long m = __ballot(p == pp);
                if (m) {
                    if (p == pp) bucket[off[pp] + __popcll(m & below)] = packed;
                    off[pp] += __popcll(m);
                }
            }
        }
    }
}

// ---- K4: degree histogram from bucket (single-read) ----
__global__ __launch_bounds__(NTH, 8) void deg_hist_kernel(
        const unsigned* __restrict__ bucket, const int* __restrict__ pstart,
        float* __restrict__ degf) {
    __shared__ float hist[PART];
    int p = blockIdx.x % P_PARTS;
    int chunk = blockIdx.x / P_PARTS;
    for (int i = threadIdx.x; i < PART; i += NTH) hist[i] = 0.f;
    int b0 = pstart[p], b1 = pstart[p + 1];
    int per = (b1 - b0 + CHUNKS - 1) / CHUNKS;
    int lo = b0 + chunk * per;
    int hi = min(lo + per, b1);
    __syncthreads();
    for (int i = lo + threadIdx.x; i < hi; i += NTH)
        atomicAdd(&hist[bucket[i] >> 17], 1.0f);
    __syncthreads();
    int base = p * PART;
    for (int i = threadIdx.x; i < PART; i += NTH) {
        float v = hist[i];
        if (v != 0.f) unsafeAtomicAdd(&degf[base + i], v);
    }
}

// ---- K5: encoder (scalar): gs[n] = dinv * (GB + sum_c PReLU(Ax0+Bx1+C) U[c]) ----
__global__ __launch_bounds__(NTH) void encoder_kernel(
        const float* __restrict__ x, const float* __restrict__ consts,
        const float* __restrict__ prelu_a, const float* __restrict__ degf,
        float* __restrict__ dinv, float* __restrict__ gs, float* __restrict__ acc) {
    __shared__ float sA[32], sB[32], sC[32], sU[32];
    __shared__ float sGB;
    if (threadIdx.x < 32) {
        sA[threadIdx.x] = consts[threadIdx.x];
        sB[threadIdx.x] = consts[32 + threadIdx.x];
        sC[threadIdx.x] = consts[64 + threadIdx.x];
        sU[threadIdx.x] = consts[96 + threadIdx.x];
    }
    if (threadIdx.x == 0) sGB = consts[128];
    __syncthreads();
    float alpha = prelu_a[0];
    int n = blockIdx.x * NTH + threadIdx.x;
    if (n < N_NODES) {
        float2 xv = ((const float2*)x)[n];
        float g = sGB;
#pragma unroll
        for (int c = 0; c < 32; c++) {
            float hb = sA[c] * xv.x + sB[c] * xv.y + sC[c];
            float pc = hb >= 0.f ? hb : alpha * hb;
            g += pc * sU[c];
        }
        float di = rsqrtf(degf[n] + 1.0f);
        float gg = di * g;
        dinv[n] = di;
        gs[n] = gg;
        acc[n] = gg;  // self-loop term; finalize multiplies by dinv
    }
}

// ---- K6: scatter from bucket (single-read, dense gathers) ----
__global__ __launch_bounds__(NTH, 8) void scatter_hist_kernel(
        const unsigned* __restrict__ bucket, const int* __restrict__ pstart,
        const float* __restrict__ gs, float* __restrict__ acc) {
    __shared__ float hist[PART];
    int p = blockIdx.x % P_PARTS;
    int chunk = blockIdx.x / P_PARTS;
    for (int i = threadIdx.x; i < PART; i += NTH) hist[i] = 0.f;
    int b0 = pstart[p], b1 = pstart[p + 1];
    int per = (b1 - b0 + CHUNKS - 1) / CHUNKS;
    int lo = b0 + chunk * per;
    int hi = min(lo + per, b1);
    __syncthreads();
    for (int i = lo + threadIdx.x; i < hi; i += NTH) {
        unsigned pk = bucket[i];
        atomicAdd(&hist[pk >> 17], gs[pk & 0x1FFFF]);
    }
    __syncthreads();
    int base = p * PART;
    for (int i = threadIdx.x; i < PART; i += NTH) {
        float v = hist[i];
        if (v != 0.f) unsafeAtomicAdd(&acc[base + i], v);
    }
}

// ---- K7: finalize: out = dinv*acc + SCC ----
__global__ void finalize_kernel(const float* __restrict__ dinv, const float* __restrict__ acc,
                                const float* __restrict__ consts, float* __restrict__ out) {
    float scc = consts[129];
    int n = blockIdx.x * blockDim.x + threadIdx.x;
    if (n < N_NODES) out[n] = dinv[n] * acc[n] + scc;
}

extern "C" void kernel_launch(void* const* d_in, const int* in_sizes, int n_in,
                              void* d_out, int out_size, void* d_ws, size_t ws_size,
                              hipStream_t stream) {
    const float* x       = (const float*)d_in[0];
    const void*  ei      = d_in[1];
    const float* w1      = (const float*)d_in[2];
    const float* b1      = (const float*)d_in[3];
    const float* bn_g    = (const float*)d_in[4];
    const float* bn_b    = (const float*)d_in[5];
    const float* prelu_a = (const float*)d_in[6];
    const float* w2      = (const float*)d_in[7];
    const float* b2      = (const float*)d_in[8];
    const float* gcn_w   = (const float*)d_in[9];
    const float* gcn_b   = (const float*)d_in[10];
    const float* wb      = (const float*)d_in[11];
    const float* bb      = (const float*)d_in[12];
    float* out = (float*)d_out;

    char* base = (char*)d_ws;
    double*   bpart  = (double*)(base + OFF_BPART);
    float*    consts = (float*)(base + OFF_CONST);
    int*      pstart = (int*)(base + OFF_PSTART);
    int*      wcnt   = (int*)(base + OFF_WCNT);
    int*      sbase  = (int*)(base + OFF_SBASE);
    float*    degf   = (float*)(base + OFF_DEG);
    float*    acc    = (float*)(base + OFF_ACC);
    float*    dinv   = (float*)(base + OFF_DINV);
    float*    gs     = (float*)(base + OFF_GS);
    unsigned* bucket = (unsigned*)(base + OFF_BUCKET);

    count_kernel<<<CBLK, NTH, 0, stream>>>(x, ei, bpart, wcnt, degf);
    scan_kernel<<<1, NTH, 0, stream>>>(wcnt, sbase, pstart, bpart,
        w1, b1, bn_g, bn_b, w2, b2, gcn_w, wb, gcn_b, bb, consts);
    compact_kernel<<<CBLK, NTH, 0, stream>>>(ei, sbase, bucket);
    deg_hist_kernel<<<HBLOCKS, NTH, 0, stream>>>(bucket, pstart, degf);
    encoder_kernel<<<(N_NODES + NTH - 1) / NTH, NTH, 0, stream>>>(
        x, consts, prelu_a, degf, dinv, gs, acc);
    scatter_hist_kernel<<<HBLOCKS, NTH, 0, stream>>>(bucket, pstart, gs, acc);
    finalize_kernel<<<(N_NODES + 255) / 256, 256, 0, stream>>>(dinv, acc, consts, out);
}